// Round 6
// baseline (104.644 us; speedup 1.0000x reference)
//
#include <hip/hip_runtime.h>
#include <math.h>

#define BB 512
#define DD 128
#define KK 8
#define BOUNDARY 4

// ---------------- workspace layout (bytes) ----------------
// d      : 0       .. 1048576  (512*512 float)  row k written by A block k
// negIdx : 1048576 .. 1064960  (512*8 int)      top-8 neg rows per column
// anchor : 1064960 .. 1067008  (512 int)
// accum  : 1067008 .. 1067020  (float S, int C, uint done) init by A block 0
// All regions written unconditionally before read -> no memset needed.
//
// Key algebraic fact: boundary = int(512/128) = 4, so anchor rows belong to
// classes with <= 3 members; a column of such a class has <= 3 same-class
// candidates and top_k(k=8) therefore selects ALL of them (the -inf fills are
// masked by & sim). Hence mask_ap[i][j] == anchors[i] & (tgt[j]==tgt[i]) & i!=j
// — no positive top-k needed. Only the negative top-8 requires real selection.

// Kernel A: block k computes distance row k (symmetric matrix), writes it,
// does the neg top-8 of column k (== row k) in jax.lax.top_k order
// (descending value, lower index on tie), and the anchor flag.
__global__ __launch_bounds__(256) void dist_neg_kernel(
    const float* __restrict__ x, const int* __restrict__ tgt,
    float* __restrict__ d, int* __restrict__ negIdx, int* __restrict__ anchor,
    float* __restrict__ accumS, int* __restrict__ accumC, unsigned* __restrict__ done)
{
    __shared__ float4 xi4[DD / 4];
    __shared__ float s_vn[BB];     // same-class -> -inf, else -d  (count(-inf) = class count)
    int i = blockIdx.x;
    int t = threadIdx.x;
    if (i == 0 && t == 0) { *accumS = 0.f; *accumC = 0; *done = 0u; }
    if (t < DD / 4) xi4[t] = ((const float4*)(x + i * DD))[t];
    __syncthreads();
    int ti = tgt[i];

    // sqi with the same 4-chain structure as sqr below; for r==i the op
    // sequences are identical, so the diagonal is exactly 0.
    float q0 = 0.f, q1 = 0.f, q2 = 0.f, q3 = 0.f;
    for (int c = 0; c < DD / 4; ++c) {
        float4 a = xi4[c];
        q0 += a.x * a.x; q1 += a.y * a.y; q2 += a.z * a.z; q3 += a.w * a.w;
    }
    float sqi = (q0 + q1) + (q2 + q3);

    for (int rr = 0; rr < 2; ++rr) {
        int r = t + rr * 256;
        const float4* xr = (const float4*)(x + r * DD);
        float d0 = 0.f, d1 = 0.f, d2 = 0.f, d3 = 0.f;
        float s0 = 0.f, s1 = 0.f, s2 = 0.f, s3 = 0.f;
        for (int c = 0; c < DD / 4; ++c) {
            float4 a = xi4[c], b = xr[c];
            d0 += a.x * b.x; d1 += a.y * b.y; d2 += a.z * b.z; d3 += a.w * b.w;
            s0 += b.x * b.x; s1 += b.y * b.y; s2 += b.z * b.z; s3 += b.w * b.w;
        }
        float dot = (d0 + d1) + (d2 + d3);
        float sqr = (s0 + s1) + (s2 + s3);
        float dsq = fmaxf((sqi + sqr) - 2.f * dot, 0.f);
        float dv = (dsq == 0.f) ? 0.f : sqrtf(dsq);
        d[i * BB + r] = dv;                        // coalesced; symmetric by construction
        s_vn[r] = (tgt[r] == ti) ? -INFINITY : -dv;
    }
    __syncthreads();

    int wave = t >> 6, lane = t & 63;
    if (wave == 0) {
        // hard negatives: top-8 largest -d among different-class rows
        float v[8];
        for (int q = 0; q < 8; ++q) v[q] = s_vn[q * 64 + lane];
        for (int pass = 0; pass < KK; ++pass) {
            float bv = -INFINITY; int bq = -1;
            for (int q = 0; q < 8; ++q)
                if (v[q] > bv) { bv = v[q]; bq = q; }   // strict > keeps lowest q
            int bi = (bq >= 0) ? (bq * 64 + lane) : (1 << 30);
            for (int off = 32; off > 0; off >>= 1) {
                float ov = __shfl_down(bv, off);
                int   oi = __shfl_down(bi, off);
                if (ov > bv || (ov == bv && oi < bi)) { bv = ov; bi = oi; }
            }
            bv = __shfl(bv, 0); bi = __shfl(bi, 0);
            if (lane == 0) negIdx[i * KK + pass] = (bv == -INFINITY) ? -1 : bi;
            if ((bi & 63) == lane) v[bi >> 6] = -INFINITY;
        }
    } else if (wave == 1) {
        // anchor flag: same-class count (incl. self) < boundary
        int cnt = 0;
        for (int q = 0; q < 8; ++q)
            cnt += (s_vn[q * 64 + lane] == -INFINITY) ? 1 : 0;
        for (int off = 32; off > 0; off >>= 1) cnt += __shfl_down(cnt, off);
        if (lane == 0) anchor[i] = (cnt < BOUNDARY) ? 1 : 0;
    }
}

// Kernel B: one wave per row i. Anchors gather their (tiny) positive and
// negative column lists and accumulate the hinge terms; the last block to
// arrive (fenced done-counter) finalizes the division.
__global__ __launch_bounds__(64) void loss_kernel(
    const float* __restrict__ d, const int* __restrict__ tgt,
    const int* __restrict__ negIdx, const int* __restrict__ anchor,
    float* __restrict__ accumS, int* __restrict__ accumC, unsigned* __restrict__ done,
    float* __restrict__ out)
{
    int i = blockIdx.x;
    int lane = threadIdx.x;          // 0..63
    __shared__ int pos[8];           // anchor class size <= 3 -> np <= 2
    __shared__ int neg[BB];
    __shared__ int np_s, nn_s;
    float s = 0.f; int c = 0;

    if (anchor[i]) {
        if (lane == 0) { np_s = 0; nn_s = 0; }
        __syncthreads();
        int ti = tgt[i];
        for (int j = lane; j < BB; j += 64)
            if (j != i && tgt[j] == ti) pos[atomicAdd(&np_s, 1)] = j;
        // scan negIdx[512][8] for columns whose top-8 picked row i
        const int4* nI = (const int4*)negIdx;    // 1024 int4, half-row each
        for (int q = lane; q < BB * KK / 4; q += 64) {
            int4 v = nI[q];
            if (v.x == i || v.y == i || v.z == i || v.w == i)
                neg[atomicAdd(&nn_s, 1)] = q >> 1;   // column index
        }
        __syncthreads();
        int np = np_s, nn = nn_s;
        int tot = np * nn;
        const float* di = d + i * BB;
        for (int p = lane; p < tot; p += 64) {
            float tv = di[pos[p / nn]] - di[neg[p % nn]] + 1.0f;
            if (tv > 0.f) {
                s += tv;
                if (tv > 1e-7f) c += 1;
            }
        }
    }

    for (int off = 32; off > 0; off >>= 1) {
        s += __shfl_down(s, off);
        c += __shfl_down(c, off);
    }
    if (lane == 0) {
        if (s != 0.f) atomicAdd(accumS, s);
        if (c != 0)   atomicAdd(accumC, c);
        __threadfence();                          // release our adds
        unsigned prev = atomicAdd(done, 1u);
        if (prev == BB - 1) {                     // last block: all adds ordered before
            __threadfence();                      // acquire
            float S = atomicAdd(accumS, 0.f);     // atomic (device-coherent) reads
            int   C = atomicAdd(accumC, 0);
            out[0] = S / ((float)C + 1e-7f);
        }
    }
}

extern "C" void kernel_launch(void* const* d_in, const int* in_sizes, int n_in,
                              void* d_out, int out_size, void* d_ws, size_t ws_size,
                              hipStream_t stream) {
    const float* x   = (const float*)d_in[0];
    const int*   tgt = (const int*)d_in[1];
    float* out = (float*)d_out;

    char* ws = (char*)d_ws;
    float*    dmat   = (float*)(ws + 0);
    int*      negIdx = (int*)(ws + 1048576);
    int*      anchor = (int*)(ws + 1064960);
    float*    accumS = (float*)(ws + 1067008);
    int*      accumC = (int*)(ws + 1067012);
    unsigned* done   = (unsigned*)(ws + 1067016);

    dist_neg_kernel<<<BB, 256, 0, stream>>>(x, tgt, dmat, negIdx, anchor,
                                            accumS, accumC, done);
    loss_kernel<<<BB, 64, 0, stream>>>(dmat, tgt, negIdx, anchor,
                                       accumS, accumC, done, out);
}

// Round 7
// 86.043 us; speedup vs baseline: 1.2162x; 1.2162x over previous
//
#include <hip/hip_runtime.h>
#include <math.h>

#define BB 512
#define DD 128
#define KK 8
#define BOUNDARY 4

// ---------------- workspace layout (bytes) ----------------
// partS : 0    .. 2048   (512 float)  per-block loss partial sum
// partC : 2048 .. 4096   (512 int)    per-block hinge count
// Written unconditionally by every block -> no memset needed.
//
// Algebraic facts exploited (boundary = int(512/128) = 4):
//  * anchor rows belong to classes with <= 3 members, so the positive top-8
//    selects ALL same-class rows: mask_ap[i][j] == anchors[i] & tgt[j]==tgt[i] & i!=j.
//  * block k owns column k: its neg top-8 rows r are exactly the (i=r, k)
//    entries of mask_an, and d[r,k] is the value the block just computed.
//  * the <= 16 positive distances d[r,j] per block are recomputed directly
//    from x (one 128-dim dot each) — they feed only hinge values, not
//    selections, so accumulation-order ulps are harmless.

__global__ __launch_bounds__(256) void fused_kernel(
    const float* __restrict__ x, const int* __restrict__ tgt,
    float* __restrict__ partS, int* __restrict__ partC)
{
    __shared__ float4 xi4[DD / 4];
    __shared__ float s_d[BB];          // raw distances, column k (== row k)
    __shared__ float s_vn[BB];         // -d masked to -inf on same-class
    __shared__ float s_sq[BB];         // squared norms of all rows
    __shared__ int   s_tgt[BB];
    __shared__ int   s_cnt[128];       // class histogram
    __shared__ int   s_sel[KK];        // selected neg rows, -1 invalid
    __shared__ int   s_pr[16], s_pj[16];
    __shared__ int   s_np;
    __shared__ float sred[256];
    __shared__ int   cred[256];

    int k = blockIdx.x;
    int t = threadIdx.x;
    if (t < DD / 4) xi4[t] = ((const float4*)(x + k * DD))[t];
    if (t < 128) s_cnt[t] = 0;
    if (t == 0) s_np = 0;
    s_tgt[t]       = tgt[t];
    s_tgt[t + 256] = tgt[t + 256];
    __syncthreads();
    int tk = s_tgt[k];

    // sqk with the same 4-chain structure as sqr below -> diagonal exactly 0
    float q0 = 0.f, q1 = 0.f, q2 = 0.f, q3 = 0.f;
    for (int c = 0; c < DD / 4; ++c) {
        float4 a = xi4[c];
        q0 += a.x * a.x; q1 += a.y * a.y; q2 += a.z * a.z; q3 += a.w * a.w;
    }
    float sqk = (q0 + q1) + (q2 + q3);

    for (int rr = 0; rr < 2; ++rr) {
        int r = t + rr * 256;
        const float4* xr = (const float4*)(x + r * DD);
        float d0 = 0.f, d1 = 0.f, d2 = 0.f, d3 = 0.f;
        float s0 = 0.f, s1 = 0.f, s2 = 0.f, s3 = 0.f;
        for (int c = 0; c < DD / 4; ++c) {
            float4 a = xi4[c], b = xr[c];
            d0 += a.x * b.x; d1 += a.y * b.y; d2 += a.z * b.z; d3 += a.w * b.w;
            s0 += b.x * b.x; s1 += b.y * b.y; s2 += b.z * b.z; s3 += b.w * b.w;
        }
        float dot = (d0 + d1) + (d2 + d3);
        float sqr = (s0 + s1) + (s2 + s3);
        float dsq = fmaxf((sqk + sqr) - 2.f * dot, 0.f);
        float dv = (dsq == 0.f) ? 0.f : sqrtf(dsq);
        s_d[r]  = dv;
        s_sq[r] = sqr;
        s_vn[r] = (s_tgt[r] == tk) ? -INFINITY : -dv;
    }
    __syncthreads();

    int wave = t >> 6, lane = t & 63;
    if (wave == 0) {
        // neg top-8: largest -d among different-class rows (lax.top_k order:
        // descending value, lower index on tie) — byte-identical to round 6
        float v[8];
        for (int q = 0; q < 8; ++q) v[q] = s_vn[q * 64 + lane];
        for (int pass = 0; pass < KK; ++pass) {
            float bv = -INFINITY; int bq = -1;
            for (int q = 0; q < 8; ++q)
                if (v[q] > bv) { bv = v[q]; bq = q; }   // strict > keeps lowest q
            int bi = (bq >= 0) ? (bq * 64 + lane) : (1 << 30);
            for (int off = 32; off > 0; off >>= 1) {
                float ov = __shfl_down(bv, off);
                int   oi = __shfl_down(bi, off);
                if (ov > bv || (ov == bv && oi < bi)) { bv = ov; bi = oi; }
            }
            bv = __shfl(bv, 0); bi = __shfl(bi, 0);
            if (lane == 0) s_sel[pass] = (bv == -INFINITY) ? -1 : bi;
            if ((bi & 63) == lane) v[bi >> 6] = -INFINITY;
        }
    } else if (wave == 1) {
        // class histogram (includes self-counts)
        for (int q = 0; q < 8; ++q) atomicAdd(&s_cnt[s_tgt[q * 64 + lane]], 1);
    }
    __syncthreads();

    // collect (anchor r, positive j) pairs: 8 groups of 32 threads, one per slot
    {
        int p = t >> 5, l = t & 31;
        int r = s_sel[p];
        if (r >= 0) {
            int tr = s_tgt[r];
            if (s_cnt[tr] < BOUNDARY) {          // anchor: class size <= 3
                for (int j = l; j < BB; j += 32)
                    if (j != r && s_tgt[j] == tr) {
                        int idx = atomicAdd(&s_np, 1);
                        s_pr[idx] = r; s_pj[idx] = j;
                    }
            }
        }
    }
    __syncthreads();

    float s = 0.f; int c = 0;
    if (t < s_np) {                              // <= 16 threads active
        int r = s_pr[t], j = s_pj[t];
        const float4* xr = (const float4*)(x + r * DD);
        const float4* xj = (const float4*)(x + j * DD);
        float d0 = 0.f, d1 = 0.f, d2 = 0.f, d3 = 0.f;
        for (int cc = 0; cc < DD / 4; ++cc) {
            float4 a = xr[cc], b = xj[cc];
            d0 += a.x * b.x; d1 += a.y * b.y; d2 += a.z * b.z; d3 += a.w * b.w;
        }
        float dot = (d0 + d1) + (d2 + d3);
        float dsq = fmaxf((s_sq[r] + s_sq[j]) - 2.f * dot, 0.f);
        float dpos = (dsq == 0.f) ? 0.f : sqrtf(dsq);
        float tv = dpos - s_d[r] + 1.0f;         // d[r,j] - d[r,k] + margin
        if (tv > 0.f) { s = tv; c = (tv > 1e-7f) ? 1 : 0; }
    }
    sred[t] = s; cred[t] = c;
    __syncthreads();
    for (int off = 128; off > 0; off >>= 1) {
        if (t < off) { sred[t] += sred[t + off]; cred[t] += cred[t + off]; }
        __syncthreads();
    }
    if (t == 0) { partS[k] = sred[0]; partC[k] = cred[0]; }
}

__global__ __launch_bounds__(256) void fin_kernel(
    const float* __restrict__ partS, const int* __restrict__ partC,
    float* __restrict__ out)
{
    __shared__ float sred[256];
    __shared__ int   cred[256];
    int t = threadIdx.x;
    sred[t] = partS[t] + partS[t + 256];
    cred[t] = partC[t] + partC[t + 256];
    __syncthreads();
    for (int off = 128; off > 0; off >>= 1) {
        if (t < off) { sred[t] += sred[t + off]; cred[t] += cred[t + off]; }
        __syncthreads();
    }
    if (t == 0) out[0] = sred[0] / ((float)cred[0] + 1e-7f);
}

extern "C" void kernel_launch(void* const* d_in, const int* in_sizes, int n_in,
                              void* d_out, int out_size, void* d_ws, size_t ws_size,
                              hipStream_t stream) {
    const float* x   = (const float*)d_in[0];
    const int*   tgt = (const int*)d_in[1];
    float* out = (float*)d_out;

    char* ws = (char*)d_ws;
    float* partS = (float*)(ws + 0);
    int*   partC = (int*)(ws + 2048);

    fused_kernel<<<BB, 256, 0, stream>>>(x, tgt, partS, partC);
    fin_kernel<<<1, 256, 0, stream>>>(partS, partC, out);
}